// Round 9
// baseline (147.898 us; speedup 1.0000x reference)
//
#include <hip/hip_runtime.h>

// CTC forward NLL (warp-ctc semantics), B=32 T=1024 V=1024 L=128, S=2L+1=257.
// Phase 1 (k_lse_gather): per-(b,t) softmax -> LINEAR probs (blank -> pB,
//          128 target labels -> packed pQ rows, cols >= tgtlen zeroed).
// Phase 1b (k_pair): bitonic-sort batches by loglen, emit perm[32] so each
//          wave gets a length-matched PAIR of batches.
// Phase 2 (k_ctc_alpha2): one wave per batch PAIR (16 blocks x 64 thr).
//          Two independent linear-domain recursions interleaved per step to
//          fill dependency bubbles (per-wave chain is the wall clock).
//          4 s-slots per lane (+1 on lane 63); pow-2 rescale every 8 steps
//          (DPP max-reduce, target 2^120); 16-timestep LDS double-buffer per
//          batch via global_load_lds; DPP wave_shr:1 for alpha[4l-1].

#define LOG2E 1.4426950408889634f
#define LN2   0.6931471805599453f

constexpr int B = 32, T = 1024, V = 1024, L = 128;
constexpr int S = 2 * L + 1;   // 257
constexpr int TS = 16;         // timesteps staged per LDS buffer per batch

// native hw transcendentals: v_exp_f32 = 2^x, v_log_f32 = log2(x)
__device__ inline float fexp2(float x) { return __builtin_amdgcn_exp2f(x); }
__device__ inline float flog2(float x) { return __builtin_amdgcn_logf(x); }

template<int CTRL>
__device__ inline float dpp_mov(float old_, float x) {
    return __int_as_float(__builtin_amdgcn_update_dpp(
        __float_as_int(old_), __float_as_int(x), CTRL, 0xF, 0xF, false));
}

// ---- Kernel 1: softmax denominator + linear-prob gather ---------------------
__global__ __launch_bounds__(256) void k_lse_gather(
    const float* __restrict__ logits, const int* __restrict__ targets,
    const int* __restrict__ tgtlen,
    float* __restrict__ pQ, float* __restrict__ pB)
{
    const int row = blockIdx.x;          // b*T + t
    const int b   = row >> 10;           // T = 1024
    const float* x = logits + (size_t)row * V;
    const int tid = threadIdx.x;

    float4 v = reinterpret_cast<const float4*>(x)[tid];   // coalesced 4 KB row
    float m = fmaxf(fmaxf(v.x, v.y), fmaxf(v.z, v.w));
    #pragma unroll
    for (int off = 32; off; off >>= 1) m = fmaxf(m, __shfl_xor(m, off));

    __shared__ float red[8];
    const int lane = tid & 63, wv = tid >> 6;
    if (lane == 0) red[wv] = m;
    __syncthreads();
    m = fmaxf(fmaxf(red[0], red[1]), fmaxf(red[2], red[3]));

    float s = fexp2((v.x - m) * LOG2E) + fexp2((v.y - m) * LOG2E)
            + fexp2((v.z - m) * LOG2E) + fexp2((v.w - m) * LOG2E);
    #pragma unroll
    for (int off = 32; off; off >>= 1) s += __shfl_xor(s, off);
    if (lane == 0) red[4 + wv] = s;
    __syncthreads();
    s = red[4] + red[5] + red[6] + red[7];

    const float lse2 = m * LOG2E + flog2(s);   // log2 of softmax denom (shifted)
    if (tid == 0) {
        pB[row] = fexp2(x[0] * LOG2E - lse2);               // blank prob
    } else if (tid <= L) {
        const int j  = tid - 1;
        const int tl = tgtlen[b];
        const int lab = targets[b * L + j];
        // zero cols j >= tl: invalid lattice slots stay exactly 0 in phase 2.
        pQ[(size_t)row * 128 + j] =
            (j < tl) ? fexp2(x[lab] * LOG2E - lse2) : 0.0f;
    }
}

// ---- Kernel 1b: sort batches by length, emit pairing permutation ------------
__global__ __launch_bounds__(64) void k_pair(const int* __restrict__ loglen,
                                             int* __restrict__ perm)
{
    const int l = threadIdx.x;
    int key = (l < B) ? (loglen[l] * 64 + l) : 0x7fffffff;  // unique keys
    #pragma unroll
    for (int k = 2; k <= 64; k <<= 1) {
        #pragma unroll
        for (int j = k >> 1; j >= 1; j >>= 1) {
            const int other = __shfl_xor(key, j);
            const bool dir = ((l & k) == 0);        // ascending region
            const bool keepMin = (((l & j) == 0) == dir);
            key = keepMin ? (other < key ? other : key)
                          : (other > key ? other : key);
        }
    }
    if (l < B) perm[l] = key & 63;
}

// ---- Kernel 2: two interleaved linear-domain alpha recursions per wave ------
__global__ __launch_bounds__(64) void k_ctc_alpha2(
    const float* __restrict__ pQ, const float* __restrict__ pB,
    const int* __restrict__ targets, const int* __restrict__ loglen,
    const int* __restrict__ tgtlen, const int* __restrict__ perm,
    float* __restrict__ out)
{
    __shared__ __align__(16) float sQ[2 * 2 * TS * 128];   // 64 KB
    __shared__ __align__(16) float sB[2 * 2 * 64];         // 2 KB
    __shared__ float al[2][S + 3];                         // ~2 KB

    const int l  = threadIdx.x;
    const int pA = __builtin_amdgcn_readfirstlane(perm[2 * blockIdx.x]);
    const int pBt= __builtin_amdgcn_readfirstlane(perm[2 * blockIdx.x + 1]);

    #define INIT(X, bval, slot)                                                \
    const int b##X  = (bval);                                                  \
    const int len##X = loglen[b##X];                                           \
    const int tl##X  = tgtlen[b##X];                                           \
    float cs1f##X, cs3f##X;                                                    \
    { const int* tg = targets + b##X * L;                                      \
      const int t2l   = tg[2 * l];                                             \
      const int t2lm1 = (l > 0) ? tg[2 * l - 1] : -3;                          \
      const int t2lp1 = tg[2 * l + 1];                                         \
      cs1f##X = (t2l != t2lm1) ? 1.0f : 0.0f;                                  \
      cs3f##X = (t2lp1 != t2l) ? 1.0f : 0.0f; }                                \
    float A0##X = (l == 0) ? pB[(size_t)b##X * T] : 0.0f;                      \
    float A1##X = (l == 0) ? pQ[(size_t)b##X * T * 128] : 0.0f;                \
    float A2##X = 0.0f, A3##X = 0.0f, A4##X = 0.0f, p3##X = 0.0f;              \
    int Se##X = 0;                                                             \
    const float* gQ##X = pQ + (size_t)b##X * T * 128 + (l & 31) * 4;           \
    const float* gB##X = pB + (size_t)b##X * T;                                \
    float* sQw##X = sQ + (slot) * (2 * TS * 128);                              \
    float* sBw##X = sB + (slot) * (2 * 64);                                    \
    float2 q##X[8]; float bb##X[8];

    INIT(A, pA, 0)
    INIT(Z, pBt, 1)        // second batch suffix Z (avoid 'B' name clash)

    #define STAGE(X, buf, t0)                                                  \
    {                                                                          \
        _Pragma("unroll")                                                      \
        for (int c = 0; c < TS / 2; ++c) {                                     \
            const int r  = (t0) + 2 * c + (l >> 5);                            \
            const int rc = (r < T) ? r : (T - 1);                              \
            const float* gp = gQ##X + (size_t)rc * 128;                        \
            __builtin_amdgcn_global_load_lds(                                  \
                (const __attribute__((address_space(1))) void*)gp,             \
                (__attribute__((address_space(3))) void*)                      \
                    (sQw##X + (buf) * (TS * 128) + 2 * c * 128), 16, 0, 0);    \
        }                                                                      \
        { const int r  = (t0) + (l & 15);                                      \
          const int rc = (r < T) ? r : (T - 1);                                \
          const float* gp = gB##X + rc;                                        \
          __builtin_amdgcn_global_load_lds(                                    \
              (const __attribute__((address_space(1))) void*)gp,               \
              (__attribute__((address_space(3))) void*)(sBw##X + (buf) * 64),  \
              4, 0, 0); }                                                      \
    }

    #define LOADG(X, buf, r0)                                                  \
    {                                                                          \
        _Pragma("unroll")                                                      \
        for (int r = 0; r < 8; ++r) {                                          \
            q##X[r] = *reinterpret_cast<const float2*>(                        \
                sQw##X + (buf) * (TS * 128) + ((r0) + r) * 128 + 2 * l);       \
            bb##X[r] = sBw##X[(buf) * 64 + (r0) + r];                          \
        }                                                                      \
    }

    #define STEP(X, i)                                                         \
    {                                                                          \
        const float pbv = bb##X[i];                                            \
        const float p1v = q##X[i].x;                                           \
        const float p3v = q##X[i].y;                                           \
        const float n0 = (A0##X + p3##X) * pbv;                                \
        const float n1 = fmaf(cs1f##X, p3##X, A1##X + A0##X) * p1v;            \
        const float n2 = (A2##X + A1##X) * pbv;                                \
        const float n3 = fmaf(cs3f##X, A1##X, A3##X + A2##X) * p3v;            \
        const float n4 = (A4##X + A3##X) * pbv;                                \
        A0##X = n0; A1##X = n1; A2##X = n2; A3##X = n3; A4##X = n4;            \
        p3##X = dpp_mov<0x138>(0.0f, A3##X);   /* wave_shr:1, lane0 <- 0 */    \
    }

    #define RESCALE(X)                                                         \
    {                                                                          \
        float m_ = fmaxf(fmaxf(A0##X, A1##X),                                  \
                         fmaxf(A2##X, fmaxf(A3##X, A4##X)));                   \
        m_ = fmaxf(m_, dpp_mov<0x111>(m_, m_));   /* row_shr:1  */             \
        m_ = fmaxf(m_, dpp_mov<0x112>(m_, m_));   /* row_shr:2  */             \
        m_ = fmaxf(m_, dpp_mov<0x114>(m_, m_));   /* row_shr:4  */             \
        m_ = fmaxf(m_, dpp_mov<0x118>(m_, m_));   /* row_shr:8  */             \
        m_ = fmaxf(m_, dpp_mov<0x142>(m_, m_));   /* row_bcast:15 */           \
        m_ = fmaxf(m_, dpp_mov<0x143>(m_, m_));   /* row_bcast:31 */           \
        const int e = (__builtin_amdgcn_readlane(__float_as_int(m_), 63)       \
                       >> 23) & 0xff;                                          \
        int kb = 374 - e;                  /* scale = 2^(247-e), biased */     \
        if (kb > 254) kb = 254;            /* clamp, self-recovers */          \
        const float sc = __int_as_float(kb << 23);                             \
        A0##X *= sc; A1##X *= sc; A2##X *= sc; A3##X *= sc; A4##X *= sc;       \
        p3##X *= sc;                                                           \
        Se##X -= (kb - 127);                                                   \
    }

    STAGE(A, 0, 1); STAGE(Z, 0, 1);      // prologue: rows 1..TS -> buf 0
    int cb = 0;
    int tb = 1;

    // joint phase: both batches, no guards (t < lenA <= lenZ, sorted pairing)
    for (; tb + TS <= lenA; tb += TS) {
        asm volatile("s_waitcnt vmcnt(0)" ::: "memory");
        STAGE(A, cb ^ 1, tb + TS); STAGE(Z, cb ^ 1, tb + TS);
        LOADG(A, cb, 0); LOADG(Z, cb, 0);
        #pragma unroll
        for (int i = 0; i < 8; ++i) { STEP(A, i); STEP(Z, i); }
        RESCALE(A); RESCALE(Z);
        LOADG(A, cb, 8); LOADG(Z, cb, 8);
        #pragma unroll
        for (int i = 0; i < 8; ++i) { STEP(A, i); STEP(Z, i); }
        RESCALE(A); RESCALE(Z);
        cb ^= 1;
    }

    // finish A (at most TS-1 guarded steps)
    int cbA = cb;
    for (int t2 = tb; t2 < lenA; t2 += TS) {
        asm volatile("s_waitcnt vmcnt(0)" ::: "memory");
        STAGE(A, cbA ^ 1, t2 + TS);
        LOADG(A, cbA, 0);
        #pragma unroll
        for (int i = 0; i < 8; ++i) { if (t2 + i < lenA) STEP(A, i); }
        if (t2 + 7 < lenA) RESCALE(A);
        LOADG(A, cbA, 8);
        #pragma unroll
        for (int i = 0; i < 8; ++i) { if (t2 + 8 + i < lenA) STEP(A, i); }
        if (t2 + 15 < lenA) RESCALE(A);
        cbA ^= 1;
    }

    // finish Z (runs to lenZ)
    int cbZ = cb;
    for (int t2 = tb; t2 < lenZ; t2 += TS) {
        asm volatile("s_waitcnt vmcnt(0)" ::: "memory");
        STAGE(Z, cbZ ^ 1, t2 + TS);
        LOADG(Z, cbZ, 0);
        #pragma unroll
        for (int i = 0; i < 8; ++i) { if (t2 + i < lenZ) STEP(Z, i); }
        if (t2 + 7 < lenZ) RESCALE(Z);
        LOADG(Z, cbZ, 8);
        #pragma unroll
        for (int i = 0; i < 8; ++i) { if (t2 + 8 + i < lenZ) STEP(Z, i); }
        if (t2 + 15 < lenZ) RESCALE(Z);
        cbZ ^= 1;
    }

    #undef STEP
    #undef RESCALE
    #undef LOADG
    #undef STAGE
    #undef INIT

    al[0][4 * l + 0] = A0A; al[0][4 * l + 1] = A1A;
    al[0][4 * l + 2] = A2A; al[0][4 * l + 3] = A3A;
    al[1][4 * l + 0] = A0Z; al[1][4 * l + 1] = A1Z;
    al[1][4 * l + 2] = A2Z; al[1][4 * l + 3] = A3Z;
    if (l == 63) { al[0][256] = A4A; al[1][256] = A4Z; }
    __syncthreads();

    if (l == 0) {
        float sum = al[0][2 * tlA] + al[0][2 * tlA - 1];
        out[bA] = -LN2 * (flog2(sum) + (float)SeA);
        sum = al[1][2 * tlZ] + al[1][2 * tlZ - 1];
        out[bZ] = -LN2 * (flog2(sum) + (float)SeZ);
    }
}

extern "C" void kernel_launch(void* const* d_in, const int* in_sizes, int n_in,
                              void* d_out, int out_size, void* d_ws, size_t ws_size,
                              hipStream_t stream) {
    const float* logits  = (const float*)d_in[0];
    const int*   targets = (const int*)d_in[1];
    const int*   loglen  = (const int*)d_in[2];
    const int*   tgtlen  = (const int*)d_in[3];
    float* out = (float*)d_out;
    float* pQ = (float*)d_ws;                                // B*T*128 floats
    float* pB = pQ + (size_t)B * T * 128;                    // B*T floats
    int*   perm = (int*)(pB + (size_t)B * T);                // 32 ints

    k_lse_gather<<<B * T, 256, 0, stream>>>(logits, targets, tgtlen, pQ, pB);
    k_pair<<<1, 64, 0, stream>>>(loglen, perm);
    k_ctc_alpha2<<<B / 2, 64, 0, stream>>>(pQ, pB, targets, loglen, tgtlen,
                                           perm, out);
}